// Round 1
// baseline (913.318 us; speedup 1.0000x reference)
//
#include <hip/hip_runtime.h>
#include <math.h>

#define NCH     129
#define NT      250
#define DINNER  256
#define DSTATE  16
#define NHEADS  4
#define DPROJ   548   // z(256) + xh(256) + B(16) + C(16) + dt(4)
#define TC      16    // timesteps per chunk; 250 = 15*16 + 10
#define MT      35    // M tiles of 16 (560 >= 548)
#define KS4     4     // K steps of 32 (c=0..127); c=128 via VALU
#define ZR      17    // zxbuf col stride (16 cols + 1 pad)
#define XK      136   // xh/xl row stride in shorts (16B-aligned)

typedef __attribute__((ext_vector_type(8))) short short8;
typedef __attribute__((ext_vector_type(4))) float f32x4;

template<int N> struct IC { static constexpr int value = N; };

__device__ __forceinline__ float silu_f(float x) { return x / (1.f + __expf(-x)); }

template<int CTRL>
__device__ __forceinline__ float dstep(float v) {
    int t = __builtin_amdgcn_update_dpp(0, __float_as_int(v), CTRL, 0xF, 0xF, true);
    return v + __int_as_float(t);
}
__device__ __forceinline__ float wave_sum63(float v) {
    v = dstep<0xB1>(v);  v = dstep<0x4E>(v);  v = dstep<0x141>(v);
    v = dstep<0x140>(v); v = dstep<0x142>(v); v = dstep<0x143>(v);
    return v;   // lane 63 = total
}
__device__ __forceinline__ float rdlane(float v, int l) {
    return __uint_as_float(__builtin_amdgcn_readlane(__float_as_uint(v), l));
}
__device__ __forceinline__ unsigned short f2bf(float f) {   // RNE
    unsigned u = __float_as_uint(f);
    u += 0x7FFF + ((u >> 16) & 1);
    return (unsigned short)(u >> 16);
}
__device__ __forceinline__ float bf2f(unsigned short h) {
    return __uint_as_float(((unsigned)h) << 16);
}

// ---------- prep: W2t[c][j] = in_proj_w @ mixer_w (fused); bias2[j] ----------
__global__ __launch_bounds__(256) void k_prep_w2(const float* __restrict__ in_proj_w,
                                                 const float* __restrict__ mixer_w,
                                                 const float* __restrict__ mixer_b,
                                                 float* __restrict__ w2t,
                                                 float* __restrict__ bias2) {
    int j = blockIdx.x;
    int c = threadIdx.x;
    if (c < NCH) {
        float acc = 0.f;
        for (int d = 0; d < 128; ++d)
            acc += in_proj_w[j * 128 + d] * mixer_w[d * NCH + c];
        w2t[(size_t)c * DPROJ + j] = acc;
    } else if (c == NCH) {
        float acc = 0.f;
        for (int d = 0; d < 128; ++d)
            acc += in_proj_w[j * 128 + d] * mixer_b[d];
        bias2[j] = acc;
    }
}

// ---------- prep: v[i] = head_w @ out_proj_w ----------
__global__ __launch_bounds__(256) void k_prep_v(const float* __restrict__ head_w,
                                                const float* __restrict__ out_proj_w,
                                                float* __restrict__ v) {
    int i = threadIdx.x;
    float acc = 0.f;
    for (int d = 0; d < 128; ++d)
        acc += head_w[d] * out_proj_w[(size_t)d * DINNER + i];
    v[i] = acc;
}

// ---------- prep: split-bf16 A-frags of W2 (KS4 k-steps, c<128), 16x16x32 layout ----------
__global__ __launch_bounds__(64) void k_prep_frag(const float* __restrict__ w2t,
                                                  unsigned short* __restrict__ ahi,
                                                  unsigned short* __restrict__ alo) {
    int mt = blockIdx.x, ks = blockIdx.y;
    int lane = threadIdx.x;
    int m = mt * 16 + (lane & 15);
    size_t base = (((size_t)(mt * KS4 + ks)) * 64 + lane) * 8;
    for (int i = 0; i < 8; ++i) {
        int k = ks * 32 + (lane >> 4) * 8 + i;   // < 128 always
        float v = (m < DPROJ) ? w2t[(size_t)k * DPROJ + m] : 0.f;
        unsigned short hb = f2bf(v);
        ahi[base + i] = hb;
        alo[base + i] = f2bf(v - bf2f(hb));
    }
}

// ---------- fused: 1 batch/block, 320 thr = 5 waves, 2 blocks/CU ----------
// waves 0-3: main (64 channels = 1 head each); wave 4: aux (staging + B/C/dt).
__global__ __launch_bounds__(320, 3) void k_fused(
    const float* __restrict__ x,        // [B,129,250]
    const unsigned short* __restrict__ ahi,
    const unsigned short* __restrict__ alo,
    const float* __restrict__ w2t,      // [129,548] (row 128 used)
    const float* __restrict__ bias2,
    const float* __restrict__ conv_w,
    const float* __restrict__ conv_b,
    const float* __restrict__ dt_bias,
    const float* __restrict__ A_log,
    const float* __restrict__ Dv,
    const float* __restrict__ norm_w,
    const float* __restrict__ vv,
    const float* __restrict__ head_b,
    float* __restrict__ out)
{
    __shared__ short xh[TC * XK];             // bf16-hi of x chunk, [tt][k]
    __shared__ short xl[TC * XK];             // bf16-lo
    __shared__ float x128buf[2][TC];          // c=128 raw, [parity][tt]
    __shared__ float zxbuf[DPROJ * ZR];       // [j][tt]
    __shared__ float bcbuf[TC][32];           // [tt][0..15 B | 16..31 C]
    __shared__ float dtbuf[TC][NHEADS];
    __shared__ float dAbuf[TC][NHEADS];
    __shared__ float smp[2][TC][8];           // [parity][tt][2 per wave]

    const int b    = blockIdx.x;
    const int tid  = threadIdx.x;
    const int lane = tid & 63;
    const int wv   = tid >> 6;                // 0..4
    const bool isMain = (wv < 4);
    const int p    = (wv << 6) | lane;        // main channel (valid if isMain)
    const int q    = lane;
    const int tcol = lane & 15;
    const int quad = lane >> 4;
    const bool isFold = (wv == 0);

    const float* w128 = w2t + (size_t)128 * DPROJ;

    float bz = 0.f, bx = 0.f, w1z = 0.f, w1x = 0.f;
    float cw0 = 0.f, cw1 = 0.f, cw2 = 0.f, cw3 = 0.f, ccb = 0.f;
    float dtb = 0.f, Ah = 0.f, Dh = 0.f, nv = 0.f;
    if (isMain) {
        bz = bias2[p];          w1z = w128[p];
        bx = bias2[DINNER + p]; w1x = w128[DINNER + p];
        cw0 = conv_w[p * 4 + 0]; cw1 = conv_w[p * 4 + 1];
        cw2 = conv_w[p * 4 + 2]; cw3 = conv_w[p * 4 + 3];
        ccb = conv_b[p];
        Dh = Dv[wv];
        nv = norm_w[p] * vv[p];
    } else if (q < 36) {
        bx  = bias2[2 * DINNER + q];
        w1x = w128[2 * DINNER + q];
        if (q < 32) {
            int ch = DINNER + q;
            cw0 = conv_w[ch * 4 + 0]; cw1 = conv_w[ch * 4 + 1];
            cw2 = conv_w[ch * 4 + 2]; cw3 = conv_w[ch * 4 + 3];
            ccb = conv_b[ch];
        } else {
            int h = q - 32;
            dtb = dt_bias[h];
            Ah  = -expf(A_log[h]);
        }
    }

    float za[TC], xa[TC], hs[DSTATE];
    float c1 = 0.f, c2 = 0.f, c3 = 0.f, outacc = 0.f;
#pragma unroll
    for (int n = 0; n < DSTATE; ++n) hs[n] = 0.f;

    const float* xb = x + (size_t)b * NCH * NT;
    float2 pr[17];

    auto load_chunk = [&](int t0, auto Lc) {
        constexpr int L  = decltype(Lc)::value;
        constexpr int HP = (L >= 2) ? L / 2 : 1;
        constexpr int PAIRS = NCH * HP;
#pragma unroll
        for (int k = 0; k * 64 < PAIRS; ++k) {
            int u = lane + 64 * k;
            if (u < PAIRS) {
                int c = u / HP, tp = u - c * HP;
                pr[k] = *(const float2*)(xb + c * NT + t0 + 2 * tp);
            }
        }
    };
    auto store_chunk = [&](auto Lc, int nxtpar) {
        constexpr int L  = decltype(Lc)::value;
        constexpr int HP = (L >= 2) ? L / 2 : 1;
        constexpr int PAIRS = NCH * HP;
#pragma unroll
        for (int k = 0; k * 64 < PAIRS; ++k) {
            int u = lane + 64 * k;
            if (u < PAIRS) {
                int c = u / HP, tp = u - c * HP;
                float2 v = pr[k];
                if (c < 128) {
                    int row = 2 * tp;
                    unsigned short h0 = f2bf(v.x), h1 = f2bf(v.y);
                    xh[row * XK + c]       = (short)h0;
                    xh[(row + 1) * XK + c] = (short)h1;
                    xl[row * XK + c]       = (short)f2bf(v.x - bf2f(h0));
                    xl[(row + 1) * XK + c] = (short)f2bf(v.y - bf2f(h1));
                } else {
                    x128buf[nxtpar][2 * tp]     = v.x;
                    x128buf[nxtpar][2 * tp + 1] = v.y;
                }
            }
        }
    };

    // prologue: stage chunk 0 (parity 0)
    if (!isMain) { load_chunk(0, IC<TC>{}); store_chunk(IC<TC>{}, 0); }
    __syncthreads();

    auto stage = [&](auto CLc, auto NLc, int s) {
        constexpr int CL = decltype(CLc)::value;
        constexpr int NL = decltype(NLc)::value;
        const int cur = s & 1;

        // ---------------- P1: MFMA GEMM (reg-double-buffered A-frags) --------
        if (isMain) {
            short8 bh[KS4], bl[KS4];
#pragma unroll
            for (int ks = 0; ks < KS4; ++ks) {
                bh[ks] = *(const short8*)&xh[tcol * XK + ks * 32 + quad * 8];
                bl[ks] = *(const short8*)&xl[tcol * XK + ks * 32 + quad * 8];
            }
            short8 f0h[KS4], f0l[KS4], f1h[KS4], f1l[KS4];
            auto loadA = [&](int mt, short8 (&fh)[KS4], short8 (&fl)[KS4]) {
#pragma unroll
                for (int ks = 0; ks < KS4; ++ks) {
                    size_t fo = (((size_t)(mt * KS4 + ks)) * 64 + lane) * 8;
                    fh[ks] = *(const short8*)(ahi + fo);
                    fl[ks] = *(const short8*)(alo + fo);
                }
            };
            auto tileC = [&](int mt, short8 (&fh)[KS4], short8 (&fl)[KS4]) {
                f32x4 a0 = {0.f, 0.f, 0.f, 0.f};
                f32x4 a1 = {0.f, 0.f, 0.f, 0.f};
#pragma unroll
                for (int ks = 0; ks < KS4; ++ks) {
                    a0 = __builtin_amdgcn_mfma_f32_16x16x32_bf16(fh[ks], bh[ks], a0, 0, 0, 0);
                    a1 = __builtin_amdgcn_mfma_f32_16x16x32_bf16(fh[ks], bl[ks], a1, 0, 0, 0);
                    a1 = __builtin_amdgcn_mfma_f32_16x16x32_bf16(fl[ks], bh[ks], a1, 0, 0, 0);
                }
#pragma unroll
                for (int r = 0; r < 4; ++r) {
                    int j = mt * 16 + quad * 4 + r;
                    if (j < DPROJ) zxbuf[j * ZR + tcol] = a0[r] + a1[r];
                }
            };
            int mt = wv;
            loadA(mt, f0h, f0l);
            while (true) {
                if (mt + 4 < MT) loadA(mt + 4, f1h, f1l);
                tileC(mt, f0h, f0l);
                mt += 4;
                if (mt >= MT) break;
                if (mt + 4 < MT) loadA(mt + 4, f0h, f0l);
                tileC(mt, f1h, f1l);
                mt += 4;
                if (mt >= MT) break;
            }
        } else {
            if constexpr (NL > 0) load_chunk((s + 1) * TC, IC<NL>{});
        }
        __syncthreads();   // A: zxbuf ready; xh/xl consumed

        // ---------------- P2a ----------------
        if (isMain) {
            if (isFold && s > 0 && lane < TC) {   // fold prev chunk's partials
                const float* sp = smp[(s - 1) & 1][lane];
                float s1 = sp[0] + sp[2] + sp[4] + sp[6];
                float s2 = sp[1] + sp[3] + sp[5] + sp[7];
                outacc = fmaf(s2, rsqrtf(fmaf(s1, 1.f / DINNER, 1e-5f)), outacc);
            }
#pragma unroll
            for (int tt = 0; tt < CL; ++tt) {
                float xm = x128buf[cur][tt];
                float zraw = zxbuf[p * ZR + tt] + bz + w1z * xm;
                float xraw = zxbuf[(DINNER + p) * ZR + tt] + bx + w1x * xm;
                float cv = fmaf(cw3, xraw, fmaf(cw2, c1, fmaf(cw1, c2, fmaf(cw0, c3, ccb))));
                c3 = c2; c2 = c1; c1 = xraw;
                xa[tt] = silu_f(cv);
                za[tt] = silu_f(zraw);
            }
        } else {
            if constexpr (NL > 0) store_chunk(IC<NL>{}, (s + 1) & 1);
            if (q < 32) {
#pragma unroll
                for (int tt = 0; tt < CL; ++tt) {
                    float xm = x128buf[cur][tt];
                    float raw = zxbuf[(2 * DINNER + q) * ZR + tt] + bx + w1x * xm;
                    float cv = fmaf(cw3, raw, fmaf(cw2, c1, fmaf(cw1, c2, fmaf(cw0, c3, ccb))));
                    c3 = c2; c2 = c1; c1 = raw;
                    bcbuf[tt][q] = silu_f(cv);
                }
            } else if (q < 36) {
                int h = q - 32;
#pragma unroll
                for (int tt = 0; tt < CL; ++tt) {
                    float xm = x128buf[cur][tt];
                    float val = zxbuf[(544 + h) * ZR + tt] + bx + w1x * xm + dtb;
                    float dt = (val > 20.f) ? val : log1pf(expf(val));
                    dtbuf[tt][h] = dt;
                    dAbuf[tt][h] = __expf(dt * Ah);
                }
            }
        }
        __syncthreads();   // B: bc/dt ready; xh/xl restaged

        // ---------------- P2b: scan + DPP reductions ----------------
        if (isMain) {
#pragma unroll
            for (int tt = 0; tt < CL; ++tt) {
                float xv  = xa[tt];
                float g   = za[tt];
                float dtv = dtbuf[tt][wv];
                float dAv = dAbuf[tt][wv];
                float bcv = bcbuf[tt][lane & 31];
                float dx = dtv * xv;
                float y0 = 0.f, y1 = 0.f, y2 = 0.f, y3 = 0.f;
#pragma unroll
                for (int n = 0; n < 4; ++n) {
                    float b0 = rdlane(bcv, n),      cc0 = rdlane(bcv, DSTATE + n);
                    float b1 = rdlane(bcv, 4 + n),  cc1 = rdlane(bcv, DSTATE + 4 + n);
                    float b2v = rdlane(bcv, 8 + n), cc2 = rdlane(bcv, DSTATE + 8 + n);
                    float b3 = rdlane(bcv, 12 + n), cc3 = rdlane(bcv, DSTATE + 12 + n);
                    hs[n]      = fmaf(hs[n],      dAv, dx * b0);  y0 = fmaf(hs[n],      cc0, y0);
                    hs[4 + n]  = fmaf(hs[4 + n],  dAv, dx * b1);  y1 = fmaf(hs[4 + n],  cc1, y1);
                    hs[8 + n]  = fmaf(hs[8 + n],  dAv, dx * b2v); y2 = fmaf(hs[8 + n],  cc2, y2);
                    hs[12 + n] = fmaf(hs[12 + n], dAv, dx * b3);  y3 = fmaf(hs[12 + n], cc3, y3);
                }
                float val = fmaf(Dh, xv, (y0 + y1) + (y2 + y3)) * g;
                float s1 = wave_sum63(val * val);
                float s2 = wave_sum63(val * nv);
                if (lane == 63) {
                    smp[cur][tt][2 * wv]     = s1;
                    smp[cur][tt][2 * wv + 1] = s2;
                }
            }
        }
        // no barrier here: next P1 doesn't touch smp/bcbuf; zxbuf reads done pre-B
    };

#pragma unroll 1
    for (int s = 0; s <= 13; ++s) stage(IC<16>{}, IC<16>{}, s);
    stage(IC<16>{}, IC<10>{}, 14);
    stage(IC<10>{}, IC<0>{}, 15);
    __syncthreads();

    if (isFold) {
        if (lane < 10) {   // fold tail chunk (stage 15, parity 1, CL=10)
            const float* sp = smp[1][lane];
            float s1 = sp[0] + sp[2] + sp[4] + sp[6];
            float s2 = sp[1] + sp[3] + sp[5] + sp[7];
            outacc = fmaf(s2, rsqrtf(fmaf(s1, 1.f / DINNER, 1e-5f)), outacc);
        }
        float tot = wave_sum63(outacc);
        if (lane == 63) out[b] = head_b[0] + tot * (1.f / NT);
    }
}

extern "C" void kernel_launch(void* const* d_in, const int* in_sizes, int n_in,
                              void* d_out, int out_size, void* d_ws, size_t ws_size,
                              hipStream_t stream) {
    const float* x         = (const float*)d_in[0];
    const float* mixer_w   = (const float*)d_in[1];
    const float* mixer_b   = (const float*)d_in[2];
    const float* in_proj_w = (const float*)d_in[3];
    const float* conv_w    = (const float*)d_in[4];
    const float* conv_b    = (const float*)d_in[5];
    const float* dt_bias   = (const float*)d_in[6];
    const float* A_log     = (const float*)d_in[7];
    const float* Dp        = (const float*)d_in[8];
    const float* norm_w    = (const float*)d_in[9];
    const float* out_proj_w= (const float*)d_in[10];
    const float* head_w    = (const float*)d_in[11];
    const float* head_b    = (const float*)d_in[12];
    float* out = (float*)d_out;

    int B = in_sizes[0] / (NCH * NT);   // 512

    float* ws    = (float*)d_ws;
    float* w2t   = ws;                          // 129*548 f32
    float* bias2 = w2t + (size_t)NCH * DPROJ;
    float* vvp   = bias2 + DPROJ;
    unsigned short* ahi = (unsigned short*)(vvp + DINNER);       // 35*4*64*8 shorts
    unsigned short* alo = ahi + (size_t)MT * KS4 * 64 * 8;

    k_prep_w2<<<DPROJ, 256, 0, stream>>>(in_proj_w, mixer_w, mixer_b, w2t, bias2);
    k_prep_v<<<1, 256, 0, stream>>>(head_w, out_proj_w, vvp);
    k_prep_frag<<<dim3(MT, KS4), 64, 0, stream>>>(w2t, ahi, alo);
    k_fused<<<B, 320, 0, stream>>>(x, ahi, alo, w2t, bias2, conv_w, conv_b,
                                   dt_bias, A_log, Dp, norm_w, vvp, head_b, out);
}

// Round 2
// 787.855 us; speedup vs baseline: 1.1592x; 1.1592x over previous
//
#include <hip/hip_runtime.h>
#include <math.h>

#define NCH     129
#define NT      250
#define DINNER  256
#define DSTATE  16
#define NHEADS  4
#define DPROJ   548   // z(256) + xh(256) + B(16) + C(16) + dt(4)
#define TC      8     // timesteps per chunk; 250 = 31*8 + 2
#define MT      35    // M tiles of 16 (560 >= 548)
#define KS4     4     // K steps of 32 (c=0..127); c=128 via VALU
#define ZR      9     // zxbuf col stride (8 cols + 1 pad)
#define XK      136   // xh/xl row stride in shorts (16B-aligned)

typedef __attribute__((ext_vector_type(8))) short short8;
typedef __attribute__((ext_vector_type(4))) float f32x4;

template<int N> struct IC { static constexpr int value = N; };

__device__ __forceinline__ float silu_f(float x) { return x / (1.f + __expf(-x)); }

template<int CTRL>
__device__ __forceinline__ float dstep(float v) {
    int t = __builtin_amdgcn_update_dpp(0, __float_as_int(v), CTRL, 0xF, 0xF, true);
    return v + __int_as_float(t);
}
__device__ __forceinline__ float wave_sum63(float v) {
    v = dstep<0xB1>(v);  v = dstep<0x4E>(v);  v = dstep<0x141>(v);
    v = dstep<0x140>(v); v = dstep<0x142>(v); v = dstep<0x143>(v);
    return v;   // lane 63 = total
}
__device__ __forceinline__ float rdlane(float v, int l) {
    return __uint_as_float(__builtin_amdgcn_readlane(__float_as_uint(v), l));
}
__device__ __forceinline__ unsigned short f2bf(float f) {   // RNE
    unsigned u = __float_as_uint(f);
    u += 0x7FFF + ((u >> 16) & 1);
    return (unsigned short)(u >> 16);
}
__device__ __forceinline__ float bf2f(unsigned short h) {
    return __uint_as_float(((unsigned)h) << 16);
}

// ---------- prep: W2t[c][j] = in_proj_w @ mixer_w (fused); bias2[j] ----------
__global__ __launch_bounds__(256) void k_prep_w2(const float* __restrict__ in_proj_w,
                                                 const float* __restrict__ mixer_w,
                                                 const float* __restrict__ mixer_b,
                                                 float* __restrict__ w2t,
                                                 float* __restrict__ bias2) {
    int j = blockIdx.x;
    int c = threadIdx.x;
    if (c < NCH) {
        float acc = 0.f;
        for (int d = 0; d < 128; ++d)
            acc += in_proj_w[j * 128 + d] * mixer_w[d * NCH + c];
        w2t[(size_t)c * DPROJ + j] = acc;
    } else if (c == NCH) {
        float acc = 0.f;
        for (int d = 0; d < 128; ++d)
            acc += in_proj_w[j * 128 + d] * mixer_b[d];
        bias2[j] = acc;
    }
}

// ---------- prep: v[i] = head_w @ out_proj_w ----------
__global__ __launch_bounds__(256) void k_prep_v(const float* __restrict__ head_w,
                                                const float* __restrict__ out_proj_w,
                                                float* __restrict__ v) {
    int i = threadIdx.x;
    float acc = 0.f;
    for (int d = 0; d < 128; ++d)
        acc += head_w[d] * out_proj_w[(size_t)d * DINNER + i];
    v[i] = acc;
}

// ---------- prep: split-bf16 A-frags of W2 (KS4 k-steps, c<128), 16x16x32 layout ----------
__global__ __launch_bounds__(64) void k_prep_frag(const float* __restrict__ w2t,
                                                  unsigned short* __restrict__ ahi,
                                                  unsigned short* __restrict__ alo) {
    int mt = blockIdx.x, ks = blockIdx.y;
    int lane = threadIdx.x;
    int m = mt * 16 + (lane & 15);
    size_t base = (((size_t)(mt * KS4 + ks)) * 64 + lane) * 8;
    for (int i = 0; i < 8; ++i) {
        int k = ks * 32 + (lane >> 4) * 8 + i;   // < 128 always
        float v = (m < DPROJ) ? w2t[(size_t)k * DPROJ + m] : 0.f;
        unsigned short hb = f2bf(v);
        ahi[base + i] = hb;
        alo[base + i] = f2bf(v - bf2f(hb));
    }
}

// ---------- fused: 1 batch/block, 320 thr = 5 waves, 2 blocks/CU ----------
// waves 0-3: main (64 channels = 1 head each); wave 4: aux (staging + B/C/dt).
__global__ __launch_bounds__(320, 3) void k_fused(
    const float* __restrict__ x,        // [B,129,250]
    const unsigned short* __restrict__ ahi,
    const unsigned short* __restrict__ alo,
    const float* __restrict__ w2t,      // [129,548] (row 128 used)
    const float* __restrict__ bias2,
    const float* __restrict__ conv_w,
    const float* __restrict__ conv_b,
    const float* __restrict__ dt_bias,
    const float* __restrict__ A_log,
    const float* __restrict__ Dv,
    const float* __restrict__ norm_w,
    const float* __restrict__ vv,
    const float* __restrict__ head_b,
    float* __restrict__ out)
{
    __shared__ short xh[16 * XK];             // bf16-hi of x chunk, [row][k]; rows 8-15 zeroed
    __shared__ short xl[16 * XK];             // bf16-lo
    __shared__ float x128buf[2][TC];          // c=128 raw, [parity][tt]
    __shared__ float zxbuf[DPROJ * ZR];       // [j][tt]
    __shared__ float bcbuf[TC][32];           // [tt][0..15 B | 16..31 C]
    __shared__ float dtbuf[TC][NHEADS];
    __shared__ float dAbuf[TC][NHEADS];
    __shared__ float smp[2][TC][8];           // [parity][tt][2 per wave]

    const int b    = blockIdx.x;
    const int tid  = threadIdx.x;
    const int lane = tid & 63;
    const int wv   = tid >> 6;                // 0..4
    const bool isMain = (wv < 4);
    const int p    = (wv << 6) | lane;        // main channel (valid if isMain)
    const int q    = lane;
    const int tcol = lane & 15;
    const int quad = lane >> 4;
    const bool isFold = (wv == 0);

    const float* w128 = w2t + (size_t)128 * DPROJ;

    float bz = 0.f, bx = 0.f, w1z = 0.f, w1x = 0.f;
    float cw0 = 0.f, cw1 = 0.f, cw2 = 0.f, cw3 = 0.f, ccb = 0.f;
    float dtb = 0.f, Ah = 0.f, Dh = 0.f, nv = 0.f;
    if (isMain) {
        bz = bias2[p];          w1z = w128[p];
        bx = bias2[DINNER + p]; w1x = w128[DINNER + p];
        cw0 = conv_w[p * 4 + 0]; cw1 = conv_w[p * 4 + 1];
        cw2 = conv_w[p * 4 + 2]; cw3 = conv_w[p * 4 + 3];
        ccb = conv_b[p];
        Dh = Dv[wv];
        nv = norm_w[p] * vv[p];
    } else if (q < 36) {
        bx  = bias2[2 * DINNER + q];
        w1x = w128[2 * DINNER + q];
        if (q < 32) {
            int ch = DINNER + q;
            cw0 = conv_w[ch * 4 + 0]; cw1 = conv_w[ch * 4 + 1];
            cw2 = conv_w[ch * 4 + 2]; cw3 = conv_w[ch * 4 + 3];
            ccb = conv_b[ch];
        } else {
            int h = q - 32;
            dtb = dt_bias[h];
            Ah  = -expf(A_log[h]);
        }
    }

    float za[TC], xa[TC], hs[DSTATE];
    float c1 = 0.f, c2 = 0.f, c3 = 0.f, outacc = 0.f;
#pragma unroll
    for (int n = 0; n < DSTATE; ++n) hs[n] = 0.f;

    const float* xb = x + (size_t)b * NCH * NT;
    float2 pr[9];

    auto load_chunk = [&](int t0, auto Lc) {
        constexpr int L  = decltype(Lc)::value;
        constexpr int HP = (L >= 2) ? L / 2 : 1;
        constexpr int PAIRS = NCH * HP;
#pragma unroll
        for (int k = 0; k * 64 < PAIRS; ++k) {
            int u = lane + 64 * k;
            if (u < PAIRS) {
                int c = u / HP, tp = u - c * HP;
                pr[k] = *(const float2*)(xb + c * NT + t0 + 2 * tp);
            }
        }
    };
    auto store_chunk = [&](auto Lc, int nxtpar) {
        constexpr int L  = decltype(Lc)::value;
        constexpr int HP = (L >= 2) ? L / 2 : 1;
        constexpr int PAIRS = NCH * HP;
#pragma unroll
        for (int k = 0; k * 64 < PAIRS; ++k) {
            int u = lane + 64 * k;
            if (u < PAIRS) {
                int c = u / HP, tp = u - c * HP;
                float2 v = pr[k];
                if (c < 128) {
                    int row = 2 * tp;
                    unsigned short h0 = f2bf(v.x), h1 = f2bf(v.y);
                    xh[row * XK + c]       = (short)h0;
                    xh[(row + 1) * XK + c] = (short)h1;
                    xl[row * XK + c]       = (short)f2bf(v.x - bf2f(h0));
                    xl[(row + 1) * XK + c] = (short)f2bf(v.y - bf2f(h1));
                } else {
                    x128buf[nxtpar][2 * tp]     = v.x;
                    x128buf[nxtpar][2 * tp + 1] = v.y;
                }
            }
        }
    };

    // prologue: zero B-frag rows 8-15 (MFMA cols 8-15 are don't-care but keep clean),
    // stage chunk 0 (parity 0)
    for (int i = tid; i < 8 * XK; i += 320) { xh[8 * XK + i] = 0; xl[8 * XK + i] = 0; }
    if (!isMain) { load_chunk(0, IC<TC>{}); store_chunk(IC<TC>{}, 0); }
    __syncthreads();

    auto stage = [&](auto CLc, auto NLc, int s) {
        constexpr int CL = decltype(CLc)::value;
        constexpr int NL = decltype(NLc)::value;
        const int cur = s & 1;

        // ---------------- P1: MFMA GEMM ----------------
        if (isMain) {
            short8 bh[KS4], bl[KS4];
#pragma unroll
            for (int ks = 0; ks < KS4; ++ks) {
                bh[ks] = *(const short8*)&xh[tcol * XK + ks * 32 + quad * 8];
                bl[ks] = *(const short8*)&xl[tcol * XK + ks * 32 + quad * 8];
            }
            for (int mt = wv; mt < MT; mt += 4) {
                f32x4 a0 = {0.f, 0.f, 0.f, 0.f};
                f32x4 a1 = {0.f, 0.f, 0.f, 0.f};
#pragma unroll
                for (int ks = 0; ks < KS4; ++ks) {
                    size_t fo = (((size_t)(mt * KS4 + ks)) * 64 + lane) * 8;
                    short8 ah = *(const short8*)(ahi + fo);
                    short8 al = *(const short8*)(alo + fo);
                    a0 = __builtin_amdgcn_mfma_f32_16x16x32_bf16(ah, bh[ks], a0, 0, 0, 0);
                    a1 = __builtin_amdgcn_mfma_f32_16x16x32_bf16(ah, bl[ks], a1, 0, 0, 0);
                    a1 = __builtin_amdgcn_mfma_f32_16x16x32_bf16(al, bh[ks], a1, 0, 0, 0);
                }
#pragma unroll
                for (int r = 0; r < 4; ++r) {
                    int j = mt * 16 + quad * 4 + r;
                    if (j < DPROJ && tcol < TC) zxbuf[j * ZR + tcol] = a0[r] + a1[r];
                }
            }
        } else {
            if constexpr (NL > 0) load_chunk((s + 1) * TC, IC<NL>{});
        }
        __syncthreads();   // A: zxbuf ready; xh/xl consumed

        // ---------------- P2a ----------------
        if (isMain) {
            if (isFold && s > 0 && lane < TC) {   // fold prev chunk's partials
                const float* sp = smp[(s - 1) & 1][lane];
                float s1 = sp[0] + sp[2] + sp[4] + sp[6];
                float s2 = sp[1] + sp[3] + sp[5] + sp[7];
                outacc = fmaf(s2, rsqrtf(fmaf(s1, 1.f / DINNER, 1e-5f)), outacc);
            }
#pragma unroll
            for (int tt = 0; tt < CL; ++tt) {
                float xm = x128buf[cur][tt];
                float zraw = zxbuf[p * ZR + tt] + bz + w1z * xm;
                float xraw = zxbuf[(DINNER + p) * ZR + tt] + bx + w1x * xm;
                float cv = fmaf(cw3, xraw, fmaf(cw2, c1, fmaf(cw1, c2, fmaf(cw0, c3, ccb))));
                c3 = c2; c2 = c1; c1 = xraw;
                xa[tt] = silu_f(cv);
                za[tt] = silu_f(zraw);
            }
        } else {
            if constexpr (NL > 0) store_chunk(IC<NL>{}, (s + 1) & 1);
            if (q < 32) {
#pragma unroll
                for (int tt = 0; tt < CL; ++tt) {
                    float xm = x128buf[cur][tt];
                    float raw = zxbuf[(2 * DINNER + q) * ZR + tt] + bx + w1x * xm;
                    float cv = fmaf(cw3, raw, fmaf(cw2, c1, fmaf(cw1, c2, fmaf(cw0, c3, ccb))));
                    c3 = c2; c2 = c1; c1 = raw;
                    bcbuf[tt][q] = silu_f(cv);
                }
            } else if (q < 36) {
                int h = q - 32;
#pragma unroll
                for (int tt = 0; tt < CL; ++tt) {
                    float xm = x128buf[cur][tt];
                    float val = zxbuf[(544 + h) * ZR + tt] + bx + w1x * xm + dtb;
                    float dt = (val > 20.f) ? val : log1pf(expf(val));
                    dtbuf[tt][h] = dt;
                    dAbuf[tt][h] = __expf(dt * Ah);
                }
            }
        }
        __syncthreads();   // B: bc/dt ready; xh/xl restaged

        // ---------------- P2b: scan + DPP reductions ----------------
        if (isMain) {
#pragma unroll
            for (int tt = 0; tt < CL; ++tt) {
                float xv  = xa[tt];
                float g   = za[tt];
                float dtv = dtbuf[tt][wv];
                float dAv = dAbuf[tt][wv];
                float bcv = bcbuf[tt][lane & 31];
                float dx = dtv * xv;
                float y0 = 0.f, y1 = 0.f, y2 = 0.f, y3 = 0.f;
#pragma unroll
                for (int n = 0; n < 4; ++n) {
                    float b0 = rdlane(bcv, n),      cc0 = rdlane(bcv, DSTATE + n);
                    float b1 = rdlane(bcv, 4 + n),  cc1 = rdlane(bcv, DSTATE + 4 + n);
                    float b2v = rdlane(bcv, 8 + n), cc2 = rdlane(bcv, DSTATE + 8 + n);
                    float b3 = rdlane(bcv, 12 + n), cc3 = rdlane(bcv, DSTATE + 12 + n);
                    hs[n]      = fmaf(hs[n],      dAv, dx * b0);  y0 = fmaf(hs[n],      cc0, y0);
                    hs[4 + n]  = fmaf(hs[4 + n],  dAv, dx * b1);  y1 = fmaf(hs[4 + n],  cc1, y1);
                    hs[8 + n]  = fmaf(hs[8 + n],  dAv, dx * b2v); y2 = fmaf(hs[8 + n],  cc2, y2);
                    hs[12 + n] = fmaf(hs[12 + n], dAv, dx * b3);  y3 = fmaf(hs[12 + n], cc3, y3);
                }
                float val = fmaf(Dh, xv, (y0 + y1) + (y2 + y3)) * g;
                float s1 = wave_sum63(val * val);
                float s2 = wave_sum63(val * nv);
                if (lane == 63) {
                    smp[cur][tt][2 * wv]     = s1;
                    smp[cur][tt][2 * wv + 1] = s2;
                }
            }
        }
        // no barrier here: next P1 doesn't touch smp/bcbuf; zxbuf reads done pre-B
    };

    stage(IC<8>{}, IC<8>{}, 0);
#pragma unroll 1
    for (int s = 1; s <= 29; ++s) stage(IC<8>{}, IC<8>{}, s);
    stage(IC<8>{}, IC<2>{}, 30);
    stage(IC<2>{}, IC<0>{}, 31);
    __syncthreads();

    if (isFold) {
        if (lane < 2) {   // fold tail chunk (stage 31, parity 1, CL=2)
            const float* sp = smp[1][lane];
            float s1 = sp[0] + sp[2] + sp[4] + sp[6];
            float s2 = sp[1] + sp[3] + sp[5] + sp[7];
            outacc = fmaf(s2, rsqrtf(fmaf(s1, 1.f / DINNER, 1e-5f)), outacc);
        }
        float tot = wave_sum63(outacc);
        if (lane == 63) out[b] = head_b[0] + tot * (1.f / NT);
    }
}

extern "C" void kernel_launch(void* const* d_in, const int* in_sizes, int n_in,
                              void* d_out, int out_size, void* d_ws, size_t ws_size,
                              hipStream_t stream) {
    const float* x         = (const float*)d_in[0];
    const float* mixer_w   = (const float*)d_in[1];
    const float* mixer_b   = (const float*)d_in[2];
    const float* in_proj_w = (const float*)d_in[3];
    const float* conv_w    = (const float*)d_in[4];
    const float* conv_b    = (const float*)d_in[5];
    const float* dt_bias   = (const float*)d_in[6];
    const float* A_log     = (const float*)d_in[7];
    const float* Dp        = (const float*)d_in[8];
    const float* norm_w    = (const float*)d_in[9];
    const float* out_proj_w= (const float*)d_in[10];
    const float* head_w    = (const float*)d_in[11];
    const float* head_b    = (const float*)d_in[12];
    float* out = (float*)d_out;

    int B = in_sizes[0] / (NCH * NT);   // 512

    float* ws    = (float*)d_ws;
    float* w2t   = ws;                          // 129*548 f32
    float* bias2 = w2t + (size_t)NCH * DPROJ;
    float* vvp   = bias2 + DPROJ;
    unsigned short* ahi = (unsigned short*)(vvp + DINNER);       // 35*4*64*8 shorts
    unsigned short* alo = ahi + (size_t)MT * KS4 * 64 * 8;

    k_prep_w2<<<DPROJ, 256, 0, stream>>>(in_proj_w, mixer_w, mixer_b, w2t, bias2);
    k_prep_v<<<1, 256, 0, stream>>>(head_w, out_proj_w, vvp);
    k_prep_frag<<<dim3(MT, KS4), 64, 0, stream>>>(w2t, ahi, alo);
    k_fused<<<B, 320, 0, stream>>>(x, ahi, alo, w2t, bias2, conv_w, conv_b,
                                   dt_bias, A_log, Dp, norm_w, vvp, head_b, out);
}

// Round 3
// 609.872 us; speedup vs baseline: 1.4976x; 1.2918x over previous
//
#include <hip/hip_runtime.h>
#include <math.h>

#define NCH     129
#define NT      250
#define DINNER  256
#define DSTATE  16
#define NHEADS  4
#define DPROJ   548   // z(256) + xh(256) + B(16) + C(16) + dt(4)
#define TC      16    // timesteps per chunk; 250 = 15*16 + 10
#define MT      35    // M tiles of 16 (560 >= 548)
#define KS4     4     // K steps of 32 (c=0..127); c=128 via VALU
#define ZR      33    // zxbuf col stride (32 cols + 1 pad)
#define XK      136   // xh/xl row stride in shorts (16B-aligned)

typedef __attribute__((ext_vector_type(8))) short short8;
typedef __attribute__((ext_vector_type(4))) float f32x4;

template<int N> struct IC { static constexpr int value = N; };

__device__ __forceinline__ float silu_f(float x) { return x / (1.f + __expf(-x)); }

template<int CTRL>
__device__ __forceinline__ float dstep(float v) {
    int t = __builtin_amdgcn_update_dpp(0, __float_as_int(v), CTRL, 0xF, 0xF, true);
    return v + __int_as_float(t);
}
__device__ __forceinline__ float wave_sum63(float v) {
    v = dstep<0xB1>(v);  v = dstep<0x4E>(v);  v = dstep<0x141>(v);
    v = dstep<0x140>(v); v = dstep<0x142>(v); v = dstep<0x143>(v);
    return v;   // lane 63 = total
}
__device__ __forceinline__ float rdlane(float v, int l) {
    return __uint_as_float(__builtin_amdgcn_readlane(__float_as_uint(v), l));
}
__device__ __forceinline__ unsigned short f2bf(float f) {   // RNE
    unsigned u = __float_as_uint(f);
    u += 0x7FFF + ((u >> 16) & 1);
    return (unsigned short)(u >> 16);
}
__device__ __forceinline__ float bf2f(unsigned short h) {
    return __uint_as_float(((unsigned)h) << 16);
}

// ---------- prep: W2t[c][j] = in_proj_w @ mixer_w (fused); bias2[j] ----------
__global__ __launch_bounds__(256) void k_prep_w2(const float* __restrict__ in_proj_w,
                                                 const float* __restrict__ mixer_w,
                                                 const float* __restrict__ mixer_b,
                                                 float* __restrict__ w2t,
                                                 float* __restrict__ bias2) {
    int j = blockIdx.x;
    int c = threadIdx.x;
    if (c < NCH) {
        float acc = 0.f;
        for (int d = 0; d < 128; ++d)
            acc += in_proj_w[j * 128 + d] * mixer_w[d * NCH + c];
        w2t[(size_t)c * DPROJ + j] = acc;
    } else if (c == NCH) {
        float acc = 0.f;
        for (int d = 0; d < 128; ++d)
            acc += in_proj_w[j * 128 + d] * mixer_b[d];
        bias2[j] = acc;
    }
}

// ---------- prep: v[i] = head_w @ out_proj_w ----------
__global__ __launch_bounds__(256) void k_prep_v(const float* __restrict__ head_w,
                                                const float* __restrict__ out_proj_w,
                                                float* __restrict__ v) {
    int i = threadIdx.x;
    float acc = 0.f;
    for (int d = 0; d < 128; ++d)
        acc += head_w[d] * out_proj_w[(size_t)d * DINNER + i];
    v[i] = acc;
}

// ---------- prep: split-bf16 A-frags of W2 (KS4 k-steps, c<128), 16x16x32 layout ----------
__global__ __launch_bounds__(64) void k_prep_frag(const float* __restrict__ w2t,
                                                  unsigned short* __restrict__ ahi,
                                                  unsigned short* __restrict__ alo) {
    int mt = blockIdx.x, ks = blockIdx.y;
    int lane = threadIdx.x;
    int m = mt * 16 + (lane & 15);
    size_t base = (((size_t)(mt * KS4 + ks)) * 64 + lane) * 8;
    for (int i = 0; i < 8; ++i) {
        int k = ks * 32 + (lane >> 4) * 8 + i;   // < 128 always
        float v = (m < DPROJ) ? w2t[(size_t)k * DPROJ + m] : 0.f;
        unsigned short hb = f2bf(v);
        ahi[base + i] = hb;
        alo[base + i] = f2bf(v - bf2f(hb));
    }
}

// ---------- fused: 2 batches/block, 768 thr = 12 waves ----------
// waves 0-3: batch0 scan (1 head each); 4-7: batch1 scan; 8-11: aux (2 per batch).
// GEMM B operand = 32 cols (2 batches x TC=16): each A-frag read feeds 6 MFMAs.
__global__ __launch_bounds__(768, 3) void k_fused(
    const float* __restrict__ x,        // [B,129,250]
    const unsigned short* __restrict__ ahi,
    const unsigned short* __restrict__ alo,
    const float* __restrict__ w2t,      // [129,548] (row 128 used)
    const float* __restrict__ bias2,
    const float* __restrict__ conv_w,
    const float* __restrict__ conv_b,
    const float* __restrict__ dt_bias,
    const float* __restrict__ A_log,
    const float* __restrict__ Dv,
    const float* __restrict__ norm_w,
    const float* __restrict__ vv,
    const float* __restrict__ head_b,
    float* __restrict__ out)
{
    __shared__ short xh[32 * XK];             // bf16-hi of x chunk, [col][k]; col = mb*16+tt
    __shared__ short xl[32 * XK];             // bf16-lo
    __shared__ float x128buf[2][2][TC];       // c=128 raw, [parity][batch][tt]
    __shared__ float zxbuf[DPROJ * ZR];       // [j][col]
    __shared__ float bcbuf[2][TC][32];        // [batch][tt][0..15 B | 16..31 C]
    __shared__ float dtbuf[2][TC][NHEADS];
    __shared__ float dAbuf[2][TC][NHEADS];
    __shared__ float smp[2][2][TC][8];        // [parity][batch][tt][2 per wave]

    const int b2   = blockIdx.x;
    const int tid  = threadIdx.x;
    const int lane = tid & 63;
    const int wv   = tid >> 6;                // 0..11
    const bool isMain = (wv < 8);
    const int mb   = isMain ? (wv >> 2) : ((wv - 8) >> 1);
    const int hf   = isMain ? 0 : ((wv - 8) & 1);
    const int p    = ((wv & 3) << 6) | lane;  // main channel (valid if isMain)
    const int q    = lane;
    const int tcol = lane & 15;
    const int quad = lane >> 4;
    const bool isFold = isMain && ((wv & 3) == 0);   // waves 0 (b0) and 4 (b1)

    const float* w128 = w2t + (size_t)128 * DPROJ;

    float bz = 0.f, bx = 0.f, w1z = 0.f, w1x = 0.f;
    float cw0 = 0.f, cw1 = 0.f, cw2 = 0.f, cw3 = 0.f, ccb = 0.f;
    float dtb = 0.f, Ah = 0.f, Dh = 0.f, nv = 0.f;
    if (isMain) {
        bz = bias2[p];          w1z = w128[p];
        bx = bias2[DINNER + p]; w1x = w128[DINNER + p];
        cw0 = conv_w[p * 4 + 0]; cw1 = conv_w[p * 4 + 1];
        cw2 = conv_w[p * 4 + 2]; cw3 = conv_w[p * 4 + 3];
        ccb = conv_b[p];
        Dh = Dv[wv & 3];
        nv = norm_w[p] * vv[p];
    } else if (q < 36) {
        bx  = bias2[2 * DINNER + q];
        w1x = w128[2 * DINNER + q];
        if (q < 32) {
            int ch = DINNER + q;
            cw0 = conv_w[ch * 4 + 0]; cw1 = conv_w[ch * 4 + 1];
            cw2 = conv_w[ch * 4 + 2]; cw3 = conv_w[ch * 4 + 3];
            ccb = conv_b[ch];
        } else {
            int h = q - 32;
            dtb = dt_bias[h];
            Ah  = -expf(A_log[h]);
        }
    }

    float za[TC], xa[TC], hs[DSTATE];
    float c1 = 0.f, c2 = 0.f, c3 = 0.f, outacc = 0.f;
#pragma unroll
    for (int n = 0; n < DSTATE; ++n) hs[n] = 0.f;

    const float* xb_aux = x + ((size_t)2 * b2 + mb) * NCH * NT;  // aux's batch
    const int hh = wv & 3;                                       // head (main)
    float2 pr[9];

    // aux wave loads L timesteps starting at t0 (t0 already includes hf*8)
    auto load_chunk = [&](int t0, auto Lc) {
        constexpr int L  = decltype(Lc)::value;
        constexpr int HP = (L >= 2) ? L / 2 : 1;
        constexpr int PAIRS = NCH * HP;
#pragma unroll
        for (int k = 0; k * 64 < PAIRS; ++k) {
            int u = lane + 64 * k;
            if (u < PAIRS) {
                int c = u / HP, tp = u - c * HP;
                pr[k] = *(const float2*)(xb_aux + c * NT + t0 + 2 * tp);
            }
        }
    };
    auto store_chunk = [&](auto Lc, int nxtpar) {
        constexpr int L  = decltype(Lc)::value;
        constexpr int HP = (L >= 2) ? L / 2 : 1;
        constexpr int PAIRS = NCH * HP;
#pragma unroll
        for (int k = 0; k * 64 < PAIRS; ++k) {
            int u = lane + 64 * k;
            if (u < PAIRS) {
                int c = u / HP, tp = u - c * HP;
                float2 v = pr[k];
                if (c < 128) {
                    int row = mb * 16 + hf * 8 + 2 * tp;
                    unsigned short h0 = f2bf(v.x), h1 = f2bf(v.y);
                    xh[row * XK + c]       = (short)h0;
                    xh[(row + 1) * XK + c] = (short)h1;
                    xl[row * XK + c]       = (short)f2bf(v.x - bf2f(h0));
                    xl[(row + 1) * XK + c] = (short)f2bf(v.y - bf2f(h1));
                } else {
                    x128buf[nxtpar][mb][hf * 8 + 2 * tp]     = v.x;
                    x128buf[nxtpar][mb][hf * 8 + 2 * tp + 1] = v.y;
                }
            }
        }
    };

    // prologue: stage chunk 0 (parity 0); each aux wave stages its 8-ts half
    if (!isMain) { load_chunk(hf * 8, IC<8>{}); store_chunk(IC<8>{}, 0); }
    __syncthreads();

    auto stage = [&](auto CLc, auto NLc, int s) {
        constexpr int CL = decltype(CLc)::value;
        constexpr int NL = decltype(NLc)::value;
        constexpr int NL0 = (NL > 8) ? 8 : NL;     // half-0 aux load count
        constexpr int NL1 = (NL > 8) ? NL - 8 : 0; // half-1 aux load count
        const int cur = s & 1;

        // ---------------- P1: MFMA GEMM (32-col B, 2 col-tiles in regs) ------
        if (isMain) {
            short8 bh0[KS4], bl0[KS4], bh1[KS4], bl1[KS4];
#pragma unroll
            for (int ks = 0; ks < KS4; ++ks) {
                bh0[ks] = *(const short8*)&xh[tcol * XK + ks * 32 + quad * 8];
                bl0[ks] = *(const short8*)&xl[tcol * XK + ks * 32 + quad * 8];
                bh1[ks] = *(const short8*)&xh[(16 + tcol) * XK + ks * 32 + quad * 8];
                bl1[ks] = *(const short8*)&xl[(16 + tcol) * XK + ks * 32 + quad * 8];
            }
            for (int mt = wv; mt < MT; mt += 8) {
                f32x4 a00 = {0.f, 0.f, 0.f, 0.f};
                f32x4 a01 = {0.f, 0.f, 0.f, 0.f};
                f32x4 a10 = {0.f, 0.f, 0.f, 0.f};
                f32x4 a11 = {0.f, 0.f, 0.f, 0.f};
#pragma unroll
                for (int ks = 0; ks < KS4; ++ks) {
                    size_t fo = (((size_t)(mt * KS4 + ks)) * 64 + lane) * 8;
                    short8 ah = *(const short8*)(ahi + fo);
                    short8 al = *(const short8*)(alo + fo);
                    a00 = __builtin_amdgcn_mfma_f32_16x16x32_bf16(ah, bh0[ks], a00, 0, 0, 0);
                    a01 = __builtin_amdgcn_mfma_f32_16x16x32_bf16(ah, bl0[ks], a01, 0, 0, 0);
                    a01 = __builtin_amdgcn_mfma_f32_16x16x32_bf16(al, bh0[ks], a01, 0, 0, 0);
                    a10 = __builtin_amdgcn_mfma_f32_16x16x32_bf16(ah, bh1[ks], a10, 0, 0, 0);
                    a11 = __builtin_amdgcn_mfma_f32_16x16x32_bf16(ah, bl1[ks], a11, 0, 0, 0);
                    a11 = __builtin_amdgcn_mfma_f32_16x16x32_bf16(al, bh1[ks], a11, 0, 0, 0);
                }
#pragma unroll
                for (int r = 0; r < 4; ++r) {
                    int j = mt * 16 + quad * 4 + r;
                    if (j < DPROJ) {
                        zxbuf[j * ZR + tcol]      = a00[r] + a01[r];
                        zxbuf[j * ZR + 16 + tcol] = a10[r] + a11[r];
                    }
                }
            }
        } else {
            if (hf == 0) { if constexpr (NL0 > 0) load_chunk((s + 1) * TC,     IC<NL0>{}); }
            else         { if constexpr (NL1 > 0) load_chunk((s + 1) * TC + 8, IC<NL1>{}); }
        }
        __syncthreads();   // A: zxbuf ready; xh/xl consumed

        // ---------------- P2a ----------------
        if (isMain) {
            if (isFold && s > 0 && lane < TC) {   // fold prev chunk's partials
                const float* sp = smp[(s - 1) & 1][mb][lane];
                float s1 = sp[0] + sp[2] + sp[4] + sp[6];
                float s2 = sp[1] + sp[3] + sp[5] + sp[7];
                outacc = fmaf(s2, rsqrtf(fmaf(s1, 1.f / DINNER, 1e-5f)), outacc);
            }
#pragma unroll
            for (int tt = 0; tt < CL; ++tt) {
                float xm = x128buf[cur][mb][tt];
                int col = mb * 16 + tt;
                float zraw = zxbuf[p * ZR + col] + bz + w1z * xm;
                float xraw = zxbuf[(DINNER + p) * ZR + col] + bx + w1x * xm;
                float cv = fmaf(cw3, xraw, fmaf(cw2, c1, fmaf(cw1, c2, fmaf(cw0, c3, ccb))));
                c3 = c2; c2 = c1; c1 = xraw;
                xa[tt] = silu_f(cv);
                za[tt] = silu_f(zraw);
            }
        } else {
            if (hf == 0) { if constexpr (NL0 > 0) store_chunk(IC<NL0>{}, (s + 1) & 1); }
            else         { if constexpr (NL1 > 0) store_chunk(IC<NL1>{}, (s + 1) & 1); }
            // conv recurrence over t must stay on ONE wave per batch -> hf==0 does all CL
            if (hf == 0) {
                if (q < 32) {
#pragma unroll
                    for (int tt = 0; tt < CL; ++tt) {
                        float xm = x128buf[cur][mb][tt];
                        float raw = zxbuf[(2 * DINNER + q) * ZR + mb * 16 + tt] + bx + w1x * xm;
                        float cv = fmaf(cw3, raw, fmaf(cw2, c1, fmaf(cw1, c2, fmaf(cw0, c3, ccb))));
                        c3 = c2; c2 = c1; c1 = raw;
                        bcbuf[mb][tt][q] = silu_f(cv);
                    }
                } else if (q < 36) {
                    int h = q - 32;
#pragma unroll
                    for (int tt = 0; tt < CL; ++tt) {
                        float xm = x128buf[cur][mb][tt];
                        float val = zxbuf[(544 + h) * ZR + mb * 16 + tt] + bx + w1x * xm + dtb;
                        float dt = (val > 20.f) ? val : log1pf(expf(val));
                        dtbuf[mb][tt][h] = dt;
                        dAbuf[mb][tt][h] = __expf(dt * Ah);
                    }
                }
            }
        }
        __syncthreads();   // B: bc/dt ready; xh/xl restaged

        // ---------------- P2b: scan + DPP reductions ----------------
        if (isMain) {
#pragma unroll
            for (int tt = 0; tt < CL; ++tt) {
                float xv  = xa[tt];
                float g   = za[tt];
                float dtv = dtbuf[mb][tt][hh];
                float dAv = dAbuf[mb][tt][hh];
                float bcv = bcbuf[mb][tt][lane & 31];
                float dx = dtv * xv;
                float y0 = 0.f, y1 = 0.f, y2 = 0.f, y3 = 0.f;
#pragma unroll
                for (int n = 0; n < 4; ++n) {
                    float b0 = rdlane(bcv, n),      cc0 = rdlane(bcv, DSTATE + n);
                    float b1 = rdlane(bcv, 4 + n),  cc1 = rdlane(bcv, DSTATE + 4 + n);
                    float b2v = rdlane(bcv, 8 + n), cc2 = rdlane(bcv, DSTATE + 8 + n);
                    float b3 = rdlane(bcv, 12 + n), cc3 = rdlane(bcv, DSTATE + 12 + n);
                    hs[n]      = fmaf(hs[n],      dAv, dx * b0);  y0 = fmaf(hs[n],      cc0, y0);
                    hs[4 + n]  = fmaf(hs[4 + n],  dAv, dx * b1);  y1 = fmaf(hs[4 + n],  cc1, y1);
                    hs[8 + n]  = fmaf(hs[8 + n],  dAv, dx * b2v); y2 = fmaf(hs[8 + n],  cc2, y2);
                    hs[12 + n] = fmaf(hs[12 + n], dAv, dx * b3);  y3 = fmaf(hs[12 + n], cc3, y3);
                }
                float val = fmaf(Dh, xv, (y0 + y1) + (y2 + y3)) * g;
                float s1 = wave_sum63(val * val);
                float s2 = wave_sum63(val * nv);
                if (lane == 63) {
                    smp[cur][mb][tt][2 * (wv & 3)]     = s1;
                    smp[cur][mb][tt][2 * (wv & 3) + 1] = s2;
                }
            }
        }
        // no barrier here: next P1 doesn't touch smp/bcbuf; zxbuf reads done pre-B
    };

#pragma unroll 1
    for (int s = 0; s <= 13; ++s) stage(IC<16>{}, IC<16>{}, s);
    stage(IC<16>{}, IC<10>{}, 14);
    stage(IC<10>{}, IC<0>{}, 15);
    __syncthreads();

    if (isFold) {
        if (lane < 10) {   // fold tail chunk (stage 15, parity 1, CL=10)
            const float* sp = smp[1][mb][lane];
            float s1 = sp[0] + sp[2] + sp[4] + sp[6];
            float s2 = sp[1] + sp[3] + sp[5] + sp[7];
            outacc = fmaf(s2, rsqrtf(fmaf(s1, 1.f / DINNER, 1e-5f)), outacc);
        }
        float tot = wave_sum63(outacc);
        if (lane == 63) out[2 * b2 + mb] = head_b[0] + tot * (1.f / NT);
    }
}

extern "C" void kernel_launch(void* const* d_in, const int* in_sizes, int n_in,
                              void* d_out, int out_size, void* d_ws, size_t ws_size,
                              hipStream_t stream) {
    const float* x         = (const float*)d_in[0];
    const float* mixer_w   = (const float*)d_in[1];
    const float* mixer_b   = (const float*)d_in[2];
    const float* in_proj_w = (const float*)d_in[3];
    const float* conv_w    = (const float*)d_in[4];
    const float* conv_b    = (const float*)d_in[5];
    const float* dt_bias   = (const float*)d_in[6];
    const float* A_log     = (const float*)d_in[7];
    const float* Dp        = (const float*)d_in[8];
    const float* norm_w    = (const float*)d_in[9];
    const float* out_proj_w= (const float*)d_in[10];
    const float* head_w    = (const float*)d_in[11];
    const float* head_b    = (const float*)d_in[12];
    float* out = (float*)d_out;

    int B = in_sizes[0] / (NCH * NT);   // 512

    float* ws    = (float*)d_ws;
    float* w2t   = ws;                          // 129*548 f32
    float* bias2 = w2t + (size_t)NCH * DPROJ;
    float* vvp   = bias2 + DPROJ;
    unsigned short* ahi = (unsigned short*)(vvp + DINNER);       // 35*4*64*8 shorts
    unsigned short* alo = ahi + (size_t)MT * KS4 * 64 * 8;

    k_prep_w2<<<DPROJ, 256, 0, stream>>>(in_proj_w, mixer_w, mixer_b, w2t, bias2);
    k_prep_v<<<1, 256, 0, stream>>>(head_w, out_proj_w, vvp);
    k_prep_frag<<<dim3(MT, KS4), 64, 0, stream>>>(w2t, ahi, alo);
    k_fused<<<B / 2, 768, 0, stream>>>(x, ahi, alo, w2t, bias2, conv_w, conv_b,
                                       dt_bias, A_log, Dp, norm_w, vvp, head_b, out);
}